// Round 12
// baseline (492.947 us; speedup 1.0000x reference)
//
#include <hip/hip_runtime.h>
#include <hip/hip_bf16.h>
#include <stdint.h>

// Problem constants
#define BB 4
#define SS 2048
#define DD 1024
#define HH 16
#define HD 64
#define FF 4096
#define MM (BB * SS)   // 8192
#define BH (BB * HH)   // 64

typedef __bf16 bf16x8 __attribute__((ext_vector_type(8)));
typedef float f32x4 __attribute__((ext_vector_type(4)));

static __device__ __forceinline__ unsigned short f2bf(float f) {
  union { float f; unsigned u; } v; v.f = f;
  unsigned r = v.u + 0x7fffu + ((v.u >> 16) & 1u);
  return (unsigned short)(r >> 16);
}

static __device__ __forceinline__ unsigned packbf2(float a, float b) {
  __hip_bfloat162 h = __float22bfloat162_rn(float2{a, b});  // low 16 = a
  union { __hip_bfloat162 h; unsigned u; } cv; cv.h = h; return cv.u;
}

// async global->LDS, 16B per lane. Dest must be wave-uniform base; HW adds lane*16.
#define GLD_LDS16(SRC, DST)                                          \
  __builtin_amdgcn_global_load_lds(                                  \
      (const __attribute__((address_space(1))) void*)(SRC),          \
      (__attribute__((address_space(3))) void*)(DST), 16, 0, 0)

// ---------------- cast f32 -> bf16 (x) ----------------
__global__ __launch_bounds__(256) void cast_bf16_k(const float* __restrict__ in,
                                                   unsigned short* __restrict__ out) {
  size_t i = ((size_t)blockIdx.x * 256 + threadIdx.x) * 4;
  float4 v = *(const float4*)(in + i);
  ushort4 u;
  u.x = f2bf(v.x); u.y = f2bf(v.y); u.z = f2bf(v.z); u.w = f2bf(v.w);
  *(ushort4*)(out + i) = u;
}

// ---------------- transpose + cast: W[K][N] f32 -> WT[N][K] bf16 ----------------
__global__ __launch_bounds__(256) void transpose_cast_k(const float* __restrict__ in,
                                                        unsigned short* __restrict__ out,
                                                        int K, int N) {
  __shared__ float tile[32][33];
  int n0 = blockIdx.x * 32, k0 = blockIdx.y * 32;
  int tx = threadIdx.x, ty = threadIdx.y;
#pragma unroll
  for (int i = 0; i < 32; i += 8)
    tile[ty + i][tx] = in[(size_t)(k0 + ty + i) * N + n0 + tx];
  __syncthreads();
#pragma unroll
  for (int i = 0; i < 32; i += 8)
    out[(size_t)(n0 + ty + i) * K + k0 + tx] = f2bf(tile[tx][ty + i]);
}

// ---------------- GEMM 256x128, 4-phase fine interleave -----------------------------
// 512 threads = 8 waves (2M x 4N); per-wave output 128x32 (8x2 frags). BK=64.
// Double-buffered LDS (96KB -> 1 block/CU); per K-iter:
//   s_waitcnt vmcnt(0)  <- every load it waits on was issued >=2 phases earlier
//   s_barrier            (block-wide visibility: all waves counted + barrier)
//   4 phases x { ds_read quadrant frags ; issue 2 stage loads ; s_barrier ;
//                lgkmcnt(0) ; sched_barrier ; setprio(1) 8 MFMA setprio(0) }
// ds_reads issue pre-barrier (latency hides under other waves' MFMAs); per-phase
// barriers keep waves phase-converged (T3 role-split -> T5 setprio pays).
// Race-safe: WAR - all waves' reads of a buffer complete (lgkmcnt(0)) before the
// iter barrier that precedes its overwrite; RAW - vmcnt(0)+barrier at iter start.
// EPI: 0 = f32; 3 = +bias relu bf16; 4 = +bias f32; 5 = fused QKV scatter.
template <int EPI>
__global__ __launch_bounds__(512, 2) void gemm8p(const unsigned short* __restrict__ A,
                                                 const unsigned short* __restrict__ BT,
                                                 const float* __restrict__ bias,
                                                 void* __restrict__ Cout,
                                                 int N, int K) {
  constexpr int BM = 256, BN = 128;
  __shared__ __align__(16) unsigned short Al[2][BM * 64];  // 32KB x2
  __shared__ __align__(16) unsigned short Bl[2][BN * 64];  // 16KB x2
  const int t = threadIdx.x;
  const int w = t >> 6, l = t & 63, lr = l & 15, lg = l >> 4;
  const int wr = w >> 2, wc = w & 3;
  // XCD-aware chunked swizzle (requires gridDim.x*gridDim.y % 8 == 0)
  const int gx = gridDim.x;
  int lin = blockIdx.y * gx + blockIdx.x;
  const int nb = gx * gridDim.y;
  lin = (lin & 7) * (nb >> 3) + (lin >> 3);
  const int brow = (lin / gx) * BM, bcol = (lin % gx) * BN;
  f32x4 acc[8][2] = {};

  auto stageB = [&](int buf, int kt) {   // 1024 chunks, 2/thread
#pragma unroll
    for (int i = 0; i < 2; ++i) {
      int c = i * 512 + t;
      int row = c >> 3;
      int js = (c & 7) ^ (row & 7);
      GLD_LDS16(BT + (size_t)(bcol + row) * K + kt * 64 + js * 8,
                &Bl[buf][(i * 512 + w * 64) * 8]);
    }
  };
  auto stageA = [&](int buf, int kt, int half) {  // 1024 chunks/half, 2/thread
#pragma unroll
    for (int i = 0; i < 2; ++i) {
      int c = half * 1024 + i * 512 + t;
      int row = c >> 3;
      int js = (c & 7) ^ (row & 7);
      GLD_LDS16(A + (size_t)(brow + row) * K + kt * 64 + js * 8,
                &Al[buf][(half * 1024 + i * 512 + w * 64) * 8]);
    }
  };
  auto ldA = [&](bf16x8* af, int buf, int mh, int kk) {
#pragma unroll
    for (int m = 0; m < 4; ++m) {
      int row = wr * 128 + (mh * 4 + m) * 16 + lr;
      af[m] = *(const bf16x8*)&Al[buf][row * 64 + (((kk * 4 + lg) ^ (row & 7)) << 3)];
    }
  };
  auto ldB = [&](bf16x8* bf, int buf, int kk) {
#pragma unroll
    for (int n = 0; n < 2; ++n) {
      int row = wc * 32 + n * 16 + lr;
      bf[n] = *(const bf16x8*)&Bl[buf][row * 64 + (((kk * 4 + lg) ^ (row & 7)) << 3)];
    }
  };

  const int nk = K >> 6;
  stageB(0, 0); stageA(0, 0, 0); stageA(0, 0, 1);
  for (int kt = 0; kt < nk; ++kt) {
    const int p = kt & 1;
    const bool pre = (kt + 1 < nk);
    asm volatile("s_waitcnt vmcnt(0)" ::: "memory");
    __builtin_amdgcn_sched_barrier(0);
    __builtin_amdgcn_s_barrier();
    __builtin_amdgcn_sched_barrier(0);

    bf16x8 af[4], bf0[2], bf1[2];
    // phase 0: (mh0, kk0) + B kk0 ; stage B(t+1)
    ldA(af, p, 0, 0); ldB(bf0, p, 0);
    if (pre) stageB(p ^ 1, kt + 1);
    __builtin_amdgcn_s_barrier();
    asm volatile("s_waitcnt lgkmcnt(0)" ::: "memory");
    __builtin_amdgcn_sched_barrier(0);
    __builtin_amdgcn_s_setprio(1);
#pragma unroll
    for (int m = 0; m < 4; ++m)
#pragma unroll
      for (int n = 0; n < 2; ++n)
        acc[m][n] = __builtin_amdgcn_mfma_f32_16x16x32_bf16(af[m], bf0[n], acc[m][n], 0, 0, 0);
    __builtin_amdgcn_s_setprio(0);

    // phase 1: (mh1, kk0) reuse bf0 ; stage A-lo(t+1)
    ldA(af, p, 1, 0);
    if (pre) stageA(p ^ 1, kt + 1, 0);
    __builtin_amdgcn_s_barrier();
    asm volatile("s_waitcnt lgkmcnt(0)" ::: "memory");
    __builtin_amdgcn_sched_barrier(0);
    __builtin_amdgcn_s_setprio(1);
#pragma unroll
    for (int m = 0; m < 4; ++m)
#pragma unroll
      for (int n = 0; n < 2; ++n)
        acc[4 + m][n] = __builtin_amdgcn_mfma_f32_16x16x32_bf16(af[m], bf0[n], acc[4 + m][n], 0, 0, 0);
    __builtin_amdgcn_s_setprio(0);

    // phase 2: (mh0, kk1) + B kk1 ; stage A-hi(t+1)
    ldA(af, p, 0, 1); ldB(bf1, p, 1);
    if (pre) stageA(p ^ 1, kt + 1, 1);
    __builtin_amdgcn_s_barrier();
    asm volatile("s_waitcnt lgkmcnt(0)" ::: "memory");
    __builtin_amdgcn_sched_barrier(0);
    __builtin_amdgcn_s_setprio(1);
#pragma unroll
    for (int m = 0; m < 4; ++m)
#pragma unroll
      for (int n = 0; n < 2; ++n)
        acc[m][n] = __builtin_amdgcn_mfma_f32_16x16x32_bf16(af[m], bf1[n], acc[m][n], 0, 0, 0);
    __builtin_amdgcn_s_setprio(0);

    // phase 3: (mh1, kk1) reuse bf1
    ldA(af, p, 1, 1);
    __builtin_amdgcn_s_barrier();
    asm volatile("s_waitcnt lgkmcnt(0)" ::: "memory");
    __builtin_amdgcn_sched_barrier(0);
    __builtin_amdgcn_s_setprio(1);
#pragma unroll
    for (int m = 0; m < 4; ++m)
#pragma unroll
      for (int n = 0; n < 2; ++n)
        acc[4 + m][n] = __builtin_amdgcn_mfma_f32_16x16x32_bf16(af[m], bf1[n], acc[4 + m][n], 0, 0, 0);
    __builtin_amdgcn_s_setprio(0);
  }

  // epilogue: C/D layout row=(l>>4)*4+i, col=l&15  (HW-verified)
#pragma unroll
  for (int m = 0; m < 8; ++m) {
#pragma unroll
    for (int n = 0; n < 2; ++n) {
      int col = bcol + wc * 32 + n * 16 + lr;
      float bv = 0.f;
      if (EPI == 3 || EPI == 4) bv = bias[col];
#pragma unroll
      for (int i = 0; i < 4; ++i) {
        int row = brow + wr * 128 + m * 16 + lg * 4 + i;
        float v = acc[m][n][i];
        if (EPI == 0) {
          ((float*)Cout)[(size_t)row * N + col] = v;
        } else if (EPI == 3) {
          v += bv; v = v > 0.f ? v : 0.f;
          ((unsigned short*)Cout)[(size_t)row * N + col] = f2bf(v);
        } else if (EPI == 4) {
          v += bv;
          ((float*)Cout)[(size_t)row * N + col] = v;
        } else if (EPI == 5) {
          int b = row >> 11, s = row & 2047;
          int which = col >> 10, cin = col & 1023;
          int h = cin >> 6, hd = cin & 63;
          unsigned short* qb = (unsigned short*)Cout;
          if (which == 0) {        // Q, pre-scaled by 1/sqrt(HD) (exact pow2)
            qb[(((size_t)(b * HH + h)) * SS + s) * HD + hd] = f2bf(v * 0.125f);
          } else if (which == 1) { // K
            (qb + (size_t)MM * DD)[(((size_t)(b * HH + h)) * SS + s) * HD + hd] = f2bf(v);
          } else {                 // V, transposed (B,H,HD,S)
            (qb + 2 * (size_t)MM * DD)[(((size_t)(b * HH + h)) * HD + hd) * SS + s] = f2bf(v);
          }
        }
      }
    }
  }
}

// ---------------- flash attention, swapped-QK^T (R3-verified) + T5 setprio ---------
// Flat grid 2048: bh = gid&63 (batch-interleaved for load balance), qb = gid>>6.
// 4 waves x 16 q-rows. KVBLK=64, HD=64. Q bf16 (pre-scaled 0.125) in regs.
__global__ __launch_bounds__(256, 4) void attn_kernel(const unsigned short* __restrict__ Q,
                                                      const unsigned short* __restrict__ Kg,
                                                      const unsigned short* __restrict__ VT,
                                                      const int* __restrict__ vlens,
                                                      unsigned short* __restrict__ O) {
  __shared__ __align__(16) unsigned short Kt[64 * 64];  // rows = keys
  __shared__ __align__(16) unsigned short Vt[64 * 64];  // rows = d, cols = keys
  const int t = threadIdx.x;
  const int w = t >> 6, l = t & 63, lr = l & 15, lg = l >> 4;
  const int gid = blockIdx.x;
  const int bh = gid & 63, qb = gid >> 6;
  const int b = bh >> 4, h = bh & 15;
  const int q0 = qb << 6;
  const int vl = vlens[b];
  const size_t base = (size_t)bh * SS * HD;

  bf16x8 qf[2];
  {
    const int qrow = q0 + w * 16 + lr;
    qf[0] = *(const bf16x8*)(Q + base + (size_t)qrow * HD + lg * 8);
    qf[1] = *(const bf16x8*)(Q + base + (size_t)qrow * HD + 32 + lg * 8);
  }
  f32x4 o[4] = {};
  float m_r = -3.0e38f, l_r = 0.f;  // reduction domain: q = lr (replicated over lg)

  const int nkv = (vl + 63) >> 6;
  for (int kbi = 0; kbi < nkv; ++kbi) {
    const int kb = kbi << 6;
    __syncthreads();
#pragma unroll
    for (int is = 0; is < 2; ++is) {
      int c = is * 256 + t;          // 512 chunks per 8KB tile
      int row = c >> 3;
      int js = (c & 7) ^ (row & 7);
      GLD_LDS16(Kg + base + (size_t)(kb + row) * HD + js * 8,
                &Kt[(is * 256 + w * 64) * 8]);
      GLD_LDS16(VT + base + (size_t)row * SS + kb + js * 8,
                &Vt[(is * 256 + w * 64) * 8]);
    }
    __syncthreads();

    // swapped QK^T: s[n] D-layout row(key)=n*16+lg*4+i, col(q)=lr
    f32x4 s[4] = {};
    __builtin_amdgcn_s_setprio(1);
#pragma unroll
    for (int kk = 0; kk < 2; ++kk)
#pragma unroll
      for (int n = 0; n < 4; ++n) {
        int row = n * 16 + lr;
        bf16x8 kf = *(const bf16x8*)&Kt[row * 64 + (((kk * 4 + lg) ^ (row & 7)) << 3)];
        s[n] = __builtin_amdgcn_mfma_f32_16x16x32_bf16(kf, qf[kk], s[n], 0, 0, 0);
      }
    __builtin_amdgcn_s_setprio(0);

    // mask + lane-local max tree
    float sv[16];
    const int kbase = kb + lg * 4;
#pragma unroll
    for (int n = 0; n < 4; ++n)
#pragma unroll
      for (int i = 0; i < 4; ++i) {
        float v = s[n][i];
        if (kbase + n * 16 + i >= vl) v = -1.0e30f;
        sv[n * 4 + i] = v;
      }
    float tm[16];
#pragma unroll
    for (int j = 0; j < 16; ++j) tm[j] = sv[j];
#pragma unroll
    for (int st = 8; st >= 1; st >>= 1)
#pragma unroll
      for (int j = 0; j < 8; ++j)
        if (j < st) tm[j] = fmaxf(tm[j], tm[j + st]);
    float rm = tm[0];
    rm = fmaxf(rm, __shfl_xor(rm, 16));
    rm = fmaxf(rm, __shfl_xor(rm, 32));

    // defer-max (THR=8)
    if (__any(rm > m_r + 8.f)) {
      float mnew = fmaxf(m_r, rm);
      float alpha = __expf(m_r - mnew);
      m_r = mnew;
      l_r *= alpha;
      float af[4];
#pragma unroll
      for (int i = 0; i < 4; ++i) af[i] = __shfl(alpha, lg * 4 + i);  // accum domain q=lg*4+i
#pragma unroll
      for (int n = 0; n < 4; ++n)
#pragma unroll
        for (int i = 0; i < 4; ++i) o[n][i] *= af[i];
    }

    // exp + lane-local sum tree
    float p[16];
#pragma unroll
    for (int j = 0; j < 16; ++j) p[j] = __expf(sv[j] - m_r);
    float ts[16];
#pragma unroll
    for (int j = 0; j < 16; ++j) ts[j] = p[j];
#pragma unroll
    for (int st = 8; st >= 1; st >>= 1)
#pragma unroll
      for (int j = 0; j < 8; ++j)
        if (j < st) ts[j] += ts[j + st];
    float rs = ts[0];
    rs += __shfl_xor(rs, 16);
    rs += __shfl_xor(rs, 32);
    l_r += rs;

    // pack: d[n][di] = bf16 pair for keys (n*16+lg*4+2di, +1), q=lr
    unsigned pd[4][2];
#pragma unroll
    for (int n = 0; n < 4; ++n) {
      pd[n][0] = packbf2(p[n * 4 + 0], p[n * 4 + 1]);
      pd[n][1] = packbf2(p[n * 4 + 2], p[n * 4 + 3]);
    }

    // PV: A-frag lane needs P[q=lr][k=kk*32+lg*8+j]; dword jj from source lane
    // lr+16*(2*(lg&1)+(jj>>1)), reg d[2kk+(lg>>1)][jj&1].
#pragma unroll
    for (int kk = 0; kk < 2; ++kk) {
      unsigned pa[4];
#pragma unroll
      for (int jj = 0; jj < 4; ++jj) {
        int src = lr + 16 * (2 * (lg & 1) + (jj >> 1));
        unsigned rlo = __shfl(pd[2 * kk + 0][jj & 1], src);
        unsigned rhi = __shfl(pd[2 * kk + 1][jj & 1], src);
        pa[jj] = (lg & 2) ? rhi : rlo;
      }
      union { unsigned u[4]; bf16x8 v; } pb;
      pb.u[0] = pa[0]; pb.u[1] = pa[1]; pb.u[2] = pa[2]; pb.u[3] = pa[3];
      __builtin_amdgcn_s_setprio(1);
#pragma unroll
      for (int nd = 0; nd < 4; ++nd) {
        int row = nd * 16 + lr;
        bf16x8 vf = *(const bf16x8*)&Vt[row * 64 + (((kk * 4 + lg) ^ (row & 7)) << 3)];
        o[nd] = __builtin_amdgcn_mfma_f32_16x16x32_bf16(pb.v, vf, o[nd], 0, 0, 0);
      }
      __builtin_amdgcn_s_setprio(0);
    }
  }

  float linv[4];
#pragma unroll
  for (int i = 0; i < 4; ++i) linv[i] = 1.f / __shfl(l_r, lg * 4 + i);
#pragma unroll
  for (int nd = 0; nd < 4; ++nd)
#pragma unroll
    for (int i = 0; i < 4; ++i) {
      int qrow = q0 + w * 16 + lg * 4 + i;
      O[((size_t)b * SS + qrow) * DD + h * HD + nd * 16 + lr] = f2bf(o[nd][i] * linv[i]);
    }
}

// ---------------- fused add + layernorm ----------------
__global__ __launch_bounds__(256) void ln_kernel(const float* __restrict__ a,
                                                 const float* __restrict__ bsrc,
                                                 const float* __restrict__ g,
                                                 const float* __restrict__ be,
                                                 float* __restrict__ outf,
                                                 unsigned short* __restrict__ outb) {
  const int row = blockIdx.x;
  const int t = threadIdx.x;
  const float4 av = ((const float4*)(a + (size_t)row * DD))[t];
  const float4 bv = ((const float4*)(bsrc + (size_t)row * DD))[t];
  float4 s;
  s.x = av.x + bv.x; s.y = av.y + bv.y; s.z = av.z + bv.z; s.w = av.w + bv.w;
  float sum = s.x + s.y + s.z + s.w;
  float sq = s.x * s.x + s.y * s.y + s.z * s.z + s.w * s.w;
#pragma unroll
  for (int mm = 1; mm < 64; mm <<= 1) {
    sum += __shfl_xor(sum, mm);
    sq += __shfl_xor(sq, mm);
  }
  __shared__ float red[8];
  const int w = t >> 6, l = t & 63;
  if (l == 0) { red[w] = sum; red[4 + w] = sq; }
  __syncthreads();
  sum = red[0] + red[1] + red[2] + red[3];
  sq = red[4] + red[5] + red[6] + red[7];
  const float mu = sum * (1.f / (float)DD);
  const float var = sq * (1.f / (float)DD) - mu * mu;
  const float rs = rsqrtf(var + 1e-5f);
  const float4 gv = ((const float4*)g)[t];
  const float4 bev = ((const float4*)be)[t];
  float4 y;
  y.x = (s.x - mu) * rs * gv.x + bev.x;
  y.y = (s.y - mu) * rs * gv.y + bev.y;
  y.z = (s.z - mu) * rs * gv.z + bev.z;
  y.w = (s.w - mu) * rs * gv.w + bev.w;
  if (outf) ((float4*)(outf + (size_t)row * DD))[t] = y;
  if (outb) {
    ushort4 u;
    u.x = f2bf(y.x); u.y = f2bf(y.y); u.z = f2bf(y.z); u.w = f2bf(y.w);
    ((ushort4*)(outb + (size_t)row * DD))[t] = u;
  }
}

// ---------------- host ----------------
extern "C" void kernel_launch(void* const* d_in, const int* in_sizes, int n_in,
                              void* d_out, int out_size, void* d_ws, size_t ws_size,
                              hipStream_t stream) {
  (void)in_sizes; (void)n_in; (void)out_size; (void)ws_size;
  const float* x = (const float*)d_in[0];
  const int* vlen = (const int*)d_in[1];
  const float* Wq = (const float*)d_in[2];
  const float* Wk = (const float*)d_in[3];
  const float* Wv = (const float*)d_in[4];
  const float* Wo = (const float*)d_in[5];
  const float* W1 = (const float*)d_in[6];
  const float* b1 = (const float*)d_in[7];
  const float* W2 = (const float*)d_in[8];
  const float* b2 = (const float*)d_in[9];
  const float* g1 = (const float*)d_in[10];
  const float* be1 = (const float*)d_in[11];
  const float* g2 = (const float*)d_in[12];
  const float* be2 = (const float*)d_in[13];
  float* out = (float*)d_out;

  char* ws = (char*)d_ws;
  size_t off = 0;
  auto alloc = [&](size_t bytes) {
    char* p = ws + off;
    off += (bytes + 255) & ~(size_t)255;
    return p;
  };
  unsigned short* xb = (unsigned short*)alloc((size_t)MM * DD * 2);
  // WqT/WkT/WvT MUST stay contiguous (fused QKV GEMM reads them as one 3072xK matrix)
  unsigned short* WqT = (unsigned short*)alloc((size_t)DD * DD * 2);
  unsigned short* WkT = (unsigned short*)alloc((size_t)DD * DD * 2);
  unsigned short* WvT = (unsigned short*)alloc((size_t)DD * DD * 2);
  unsigned short* WoT = (unsigned short*)alloc((size_t)DD * DD * 2);
  unsigned short* W1T = (unsigned short*)alloc((size_t)FF * DD * 2);
  unsigned short* W2T = (unsigned short*)alloc((size_t)DD * FF * 2);
  // Qb/Kbb/VTb MUST stay contiguous (EPI5 scatter offsets)
  unsigned short* Qb = (unsigned short*)alloc((size_t)MM * DD * 2);   // (B,H,S,HD)
  unsigned short* Kbb = (unsigned short*)alloc((size_t)MM * DD * 2);  // (B,H,S,HD)
  unsigned short* VTb = (unsigned short*)alloc((size_t)MM * DD * 2);  // (B,H,HD,S)
  unsigned short* attnb = (unsigned short*)alloc((size_t)MM * DD * 2);
  float* proj = (float*)alloc((size_t)MM * DD * 4);
  float* res1f = (float*)alloc((size_t)MM * DD * 4);
  unsigned short* res1b = (unsigned short*)alloc((size_t)MM * DD * 2);
  unsigned short* ff1 = Qb;  // alias: Qb..attnb contiguous = 67.1MB, all dead post-attn/Wo
  float* ff2 = proj;         // alias: proj dead after LN1
  (void)Kbb; (void)VTb;

  cast_bf16_k<<<MM * DD / 1024, 256, 0, stream>>>(x, xb);
  transpose_cast_k<<<dim3(32, 32), dim3(32, 8), 0, stream>>>(Wq, WqT, DD, DD);
  transpose_cast_k<<<dim3(32, 32), dim3(32, 8), 0, stream>>>(Wk, WkT, DD, DD);
  transpose_cast_k<<<dim3(32, 32), dim3(32, 8), 0, stream>>>(Wv, WvT, DD, DD);
  transpose_cast_k<<<dim3(32, 32), dim3(32, 8), 0, stream>>>(Wo, WoT, DD, DD);
  transpose_cast_k<<<dim3(128, 32), dim3(32, 8), 0, stream>>>(W1, W1T, DD, FF);
  transpose_cast_k<<<dim3(32, 128), dim3(32, 8), 0, stream>>>(W2, W2T, FF, DD);

  // fused QKV projection: BT = [WqT;WkT;WvT] (3072 x 1024), scatter epilogue
  gemm8p<5><<<dim3(24, 32), 512, 0, stream>>>(xb, WqT, nullptr, Qb, 3072, DD);

  attn_kernel<<<dim3(2048), 256, 0, stream>>>(Qb, Kbb, VTb, vlen, attnb);

  gemm8p<0><<<dim3(8, 32), 512, 0, stream>>>(attnb, WoT, nullptr, proj, DD, DD);
  ln_kernel<<<MM, 256, 0, stream>>>(proj, x, g1, be1, res1f, res1b);
  gemm8p<3><<<dim3(32, 32), 512, 0, stream>>>(res1b, W1T, b1, ff1, FF, DD);
  gemm8p<4><<<dim3(8, 32), 512, 0, stream>>>(ff1, W2T, b2, ff2, DD, FF);
  ln_kernel<<<MM, 256, 0, stream>>>(ff2, res1f, g2, be2, out, nullptr);
}

// Round 13
// 448.499 us; speedup vs baseline: 1.0991x; 1.0991x over previous
//
#include <hip/hip_runtime.h>
#include <hip/hip_bf16.h>
#include <stdint.h>

// Problem constants
#define BB 4
#define SS 2048
#define DD 1024
#define HH 16
#define HD 64
#define FF 4096
#define MM (BB * SS)   // 8192
#define BH (BB * HH)   // 64

typedef __bf16 bf16x8 __attribute__((ext_vector_type(8)));
typedef float f32x4 __attribute__((ext_vector_type(4)));

static __device__ __forceinline__ unsigned short f2bf(float f) {
  union { float f; unsigned u; } v; v.f = f;
  unsigned r = v.u + 0x7fffu + ((v.u >> 16) & 1u);
  return (unsigned short)(r >> 16);
}

static __device__ __forceinline__ unsigned packbf2(float a, float b) {
  __hip_bfloat162 h = __float22bfloat162_rn(float2{a, b});  // low 16 = a
  union { __hip_bfloat162 h; unsigned u; } cv; cv.h = h; return cv.u;
}

// async global->LDS, 16B per lane. Dest must be wave-uniform base; HW adds lane*16.
#define GLD_LDS16(SRC, DST)                                          \
  __builtin_amdgcn_global_load_lds(                                  \
      (const __attribute__((address_space(1))) void*)(SRC),          \
      (__attribute__((address_space(3))) void*)(DST), 16, 0, 0)

// ---------------- cast f32 -> bf16 (x) ----------------
__global__ __launch_bounds__(256) void cast_bf16_k(const float* __restrict__ in,
                                                   unsigned short* __restrict__ out) {
  size_t i = ((size_t)blockIdx.x * 256 + threadIdx.x) * 4;
  float4 v = *(const float4*)(in + i);
  ushort4 u;
  u.x = f2bf(v.x); u.y = f2bf(v.y); u.z = f2bf(v.z); u.w = f2bf(v.w);
  *(ushort4*)(out + i) = u;
}

// ---------------- transpose + cast: W[K][N] f32 -> WT[N][K] bf16 ----------------
__global__ __launch_bounds__(256) void transpose_cast_k(const float* __restrict__ in,
                                                        unsigned short* __restrict__ out,
                                                        int K, int N) {
  __shared__ float tile[32][33];
  int n0 = blockIdx.x * 32, k0 = blockIdx.y * 32;
  int tx = threadIdx.x, ty = threadIdx.y;
#pragma unroll
  for (int i = 0; i < 32; i += 8)
    tile[ty + i][tx] = in[(size_t)(k0 + ty + i) * N + n0 + tx];
  __syncthreads();
#pragma unroll
  for (int i = 0; i < 32; i += 8)
    out[(size_t)(n0 + ty + i) * K + k0 + tx] = f2bf(tile[tx][ty + i]);
}

// ---------------- GEMM: C[M][N] = A[M][K] * BT[N][K]^T  (bf16 in, f32 accum) ----------
// 128x128 tile, BK=64, 4 waves (2x2), per-wave 4x4 fragments of 16x16x32 MFMA.
// LDS tiles XOR-swizzled on 16B chunks: slot(row,j) holds logical chunk j^(row&7).
// XCD-aware chunked block swizzle (T1): requires gridDim.x*gridDim.y % 8 == 0.
// __launch_bounds__(256,3): force VGPR <= ~170 so 3 blocks/CU stay resident
// (m97: 164 VGPR = 3 blocks/CU -> implicit wave-level overlap = the 900 TF plateau).
// EPI: 0 = f32 plain; 3 = +bias, relu, bf16 plain; 4 = +bias, f32 plain;
//      5 = fused QKV scatter: cols 0-1023 -> Q*(1/8) (B,H,S,HD), 1024-2047 -> K
//          (B,H,S,HD), 2048-3071 -> V^T (B,H,HD,S). Cout = Q base.
template <int EPI>
__global__ __launch_bounds__(256, 3) void gemm_bt(const unsigned short* __restrict__ A,
                                                  const unsigned short* __restrict__ BT,
                                                  const float* __restrict__ bias,
                                                  void* __restrict__ Cout,
                                                  int N, int K) {
  __shared__ __align__(16) unsigned short Al[128 * 64];
  __shared__ __align__(16) unsigned short Bl[128 * 64];
  const int t = threadIdx.x;
  const int w = t >> 6, l = t & 63, lr = l & 15, lg = l >> 4;
  const int gx = gridDim.x;
  int lin = blockIdx.y * gx + blockIdx.x;
  const int nb = gx * gridDim.y;
  lin = (lin & 7) * (nb >> 3) + (lin >> 3);
  const int brow = (lin / gx) << 7, bcol = (lin % gx) << 7;
  const int wr = w >> 1, wc = w & 1;
  f32x4 acc[4][4] = {};

  for (int kt = 0; kt < K; kt += 64) {
    __syncthreads();  // previous tile's reads done before overwrite
#pragma unroll
    for (int is = 0; is < 4; ++is) {
      int c = is * 256 + t;          // chunk index 0..1023 (16B chunks)
      int row = c >> 3;
      int js = (c & 7) ^ (row & 7);  // inverse-swizzled source chunk
      GLD_LDS16(A + (size_t)(brow + row) * K + kt + js * 8,
                &Al[(size_t)(is * 256 + w * 64) * 8]);
      GLD_LDS16(BT + (size_t)(bcol + row) * K + kt + js * 8,
                &Bl[(size_t)(is * 256 + w * 64) * 8]);
    }
    __syncthreads();  // compiler drains vmcnt(0) before barrier
#pragma unroll
    for (int kk = 0; kk < 2; ++kk) {
      bf16x8 af[4], bfr[4];
#pragma unroll
      for (int m = 0; m < 4; ++m) {
        int row = wr * 64 + m * 16 + lr;
        af[m] = *(const bf16x8*)&Al[row * 64 + (((kk * 4 + lg) ^ (row & 7)) << 3)];
      }
#pragma unroll
      for (int n = 0; n < 4; ++n) {
        int row = wc * 64 + n * 16 + lr;
        bfr[n] = *(const bf16x8*)&Bl[row * 64 + (((kk * 4 + lg) ^ (row & 7)) << 3)];
      }
#pragma unroll
      for (int m = 0; m < 4; ++m)
#pragma unroll
        for (int n = 0; n < 4; ++n)
          acc[m][n] = __builtin_amdgcn_mfma_f32_16x16x32_bf16(af[m], bfr[n], acc[m][n], 0, 0, 0);
    }
  }

  // epilogue: C/D layout row=(l>>4)*4+i, col=l&15  (HW-verified)
#pragma unroll
  for (int m = 0; m < 4; ++m) {
#pragma unroll
    for (int n = 0; n < 4; ++n) {
      int col = bcol + wc * 64 + n * 16 + lr;
      float bv = 0.f;
      if (EPI == 3 || EPI == 4) bv = bias[col];
#pragma unroll
      for (int i = 0; i < 4; ++i) {
        int row = brow + wr * 64 + m * 16 + lg * 4 + i;
        float v = acc[m][n][i];
        if (EPI == 0) {
          ((float*)Cout)[(size_t)row * N + col] = v;
        } else if (EPI == 3) {
          v += bv; v = v > 0.f ? v : 0.f;
          ((unsigned short*)Cout)[(size_t)row * N + col] = f2bf(v);
        } else if (EPI == 4) {
          v += bv;
          ((float*)Cout)[(size_t)row * N + col] = v;
        } else if (EPI == 5) {
          int b = row >> 11, s = row & 2047;
          int which = col >> 10, cin = col & 1023;
          int h = cin >> 6, hd = cin & 63;
          unsigned short* qb = (unsigned short*)Cout;
          if (which == 0) {        // Q, pre-scaled by 1/sqrt(HD) (exact pow2)
            qb[(((size_t)(b * HH + h)) * SS + s) * HD + hd] = f2bf(v * 0.125f);
          } else if (which == 1) { // K
            (qb + (size_t)MM * DD)[(((size_t)(b * HH + h)) * SS + s) * HD + hd] = f2bf(v);
          } else {                 // V, transposed (B,H,HD,S)
            (qb + 2 * (size_t)MM * DD)[(((size_t)(b * HH + h)) * HD + hd) * SS + s] = f2bf(v);
          }
        }
      }
    }
  }
}

// ---------------- flash attention, swapped-QK^T (R3-verified) + T5 setprio ---------
// Flat grid 2048: bh = gid&63 (batch-interleaved for load balance), qb = gid>>6.
// 4 waves x 16 q-rows. KVBLK=64, HD=64. Q bf16 (pre-scaled 0.125) in regs.
// QK^T computed as mfma(K, Q) -> lane owns q = lane&15; row-reduce = lane-local
// tree + 2 shfl_xor. P packed to bf16 dwords in-register, redistributed to PV
// A-frags via shfl. setprio(1) around MFMA clusters (T5).
__global__ __launch_bounds__(256, 4) void attn_kernel(const unsigned short* __restrict__ Q,
                                                      const unsigned short* __restrict__ Kg,
                                                      const unsigned short* __restrict__ VT,
                                                      const int* __restrict__ vlens,
                                                      unsigned short* __restrict__ O) {
  __shared__ __align__(16) unsigned short Kt[64 * 64];  // rows = keys
  __shared__ __align__(16) unsigned short Vt[64 * 64];  // rows = d, cols = keys
  const int t = threadIdx.x;
  const int w = t >> 6, l = t & 63, lr = l & 15, lg = l >> 4;
  const int gid = blockIdx.x;
  const int bh = gid & 63, qb = gid >> 6;
  const int b = bh >> 4, h = bh & 15;
  const int q0 = qb << 6;
  const int vl = vlens[b];
  const size_t base = (size_t)bh * SS * HD;

  bf16x8 qf[2];
  {
    const int qrow = q0 + w * 16 + lr;
    qf[0] = *(const bf16x8*)(Q + base + (size_t)qrow * HD + lg * 8);
    qf[1] = *(const bf16x8*)(Q + base + (size_t)qrow * HD + 32 + lg * 8);
  }
  f32x4 o[4] = {};
  float m_r = -3.0e38f, l_r = 0.f;  // reduction domain: q = lr (replicated over lg)

  const int nkv = (vl + 63) >> 6;
  for (int kbi = 0; kbi < nkv; ++kbi) {
    const int kb = kbi << 6;
    __syncthreads();
#pragma unroll
    for (int is = 0; is < 2; ++is) {
      int c = is * 256 + t;          // 512 chunks per 8KB tile
      int row = c >> 3;
      int js = (c & 7) ^ (row & 7);
      GLD_LDS16(Kg + base + (size_t)(kb + row) * HD + js * 8,
                &Kt[(is * 256 + w * 64) * 8]);
      GLD_LDS16(VT + base + (size_t)row * SS + kb + js * 8,
                &Vt[(is * 256 + w * 64) * 8]);
    }
    __syncthreads();

    // swapped QK^T: s[n] D-layout row(key)=n*16+lg*4+i, col(q)=lr
    f32x4 s[4] = {};
    __builtin_amdgcn_s_setprio(1);
#pragma unroll
    for (int kk = 0; kk < 2; ++kk)
#pragma unroll
      for (int n = 0; n < 4; ++n) {
        int row = n * 16 + lr;
        bf16x8 kf = *(const bf16x8*)&Kt[row * 64 + (((kk * 4 + lg) ^ (row & 7)) << 3)];
        s[n] = __builtin_amdgcn_mfma_f32_16x16x32_bf16(kf, qf[kk], s[n], 0, 0, 0);
      }
    __builtin_amdgcn_s_setprio(0);

    // mask + lane-local max tree
    float sv[16];
    const int kbase = kb + lg * 4;
#pragma unroll
    for (int n = 0; n < 4; ++n)
#pragma unroll
      for (int i = 0; i < 4; ++i) {
        float v = s[n][i];
        if (kbase + n * 16 + i >= vl) v = -1.0e30f;
        sv[n * 4 + i] = v;
      }
    float tm[16];
#pragma unroll
    for (int j = 0; j < 16; ++j) tm[j] = sv[j];
#pragma unroll
    for (int st = 8; st >= 1; st >>= 1)
#pragma unroll
      for (int j = 0; j < 8; ++j)
        if (j < st) tm[j] = fmaxf(tm[j], tm[j + st]);
    float rm = tm[0];
    rm = fmaxf(rm, __shfl_xor(rm, 16));
    rm = fmaxf(rm, __shfl_xor(rm, 32));

    // defer-max (THR=8)
    if (__any(rm > m_r + 8.f)) {
      float mnew = fmaxf(m_r, rm);
      float alpha = __expf(m_r - mnew);
      m_r = mnew;
      l_r *= alpha;
      float af[4];
#pragma unroll
      for (int i = 0; i < 4; ++i) af[i] = __shfl(alpha, lg * 4 + i);  // accum domain q=lg*4+i
#pragma unroll
      for (int n = 0; n < 4; ++n)
#pragma unroll
        for (int i = 0; i < 4; ++i) o[n][i] *= af[i];
    }

    // exp + lane-local sum tree
    float p[16];
#pragma unroll
    for (int j = 0; j < 16; ++j) p[j] = __expf(sv[j] - m_r);
    float ts[16];
#pragma unroll
    for (int j = 0; j < 16; ++j) ts[j] = p[j];
#pragma unroll
    for (int st = 8; st >= 1; st >>= 1)
#pragma unroll
      for (int j = 0; j < 8; ++j)
        if (j < st) ts[j] += ts[j + st];
    float rs = ts[0];
    rs += __shfl_xor(rs, 16);
    rs += __shfl_xor(rs, 32);
    l_r += rs;

    // pack: d[n][di] = bf16 pair for keys (n*16+lg*4+2di, +1), q=lr
    unsigned pd[4][2];
#pragma unroll
    for (int n = 0; n < 4; ++n) {
      pd[n][0] = packbf2(p[n * 4 + 0], p[n * 4 + 1]);
      pd[n][1] = packbf2(p[n * 4 + 2], p[n * 4 + 3]);
    }

    // PV: A-frag lane needs P[q=lr][k=kk*32+lg*8+j]; dword jj from source lane
    // lr+16*(2*(lg&1)+(jj>>1)), reg d[2kk+(lg>>1)][jj&1].
#pragma unroll
    for (int kk = 0; kk < 2; ++kk) {
      unsigned pa[4];
#pragma unroll
      for (int jj = 0; jj < 4; ++jj) {
        int src = lr + 16 * (2 * (lg & 1) + (jj >> 1));
        unsigned rlo = __shfl(pd[2 * kk + 0][jj & 1], src);
        unsigned rhi = __shfl(pd[2 * kk + 1][jj & 1], src);
        pa[jj] = (lg & 2) ? rhi : rlo;
      }
      union { unsigned u[4]; bf16x8 v; } pb;
      pb.u[0] = pa[0]; pb.u[1] = pa[1]; pb.u[2] = pa[2]; pb.u[3] = pa[3];
      __builtin_amdgcn_s_setprio(1);
#pragma unroll
      for (int nd = 0; nd < 4; ++nd) {
        int row = nd * 16 + lr;
        bf16x8 vf = *(const bf16x8*)&Vt[row * 64 + (((kk * 4 + lg) ^ (row & 7)) << 3)];
        o[nd] = __builtin_amdgcn_mfma_f32_16x16x32_bf16(pb.v, vf, o[nd], 0, 0, 0);
      }
      __builtin_amdgcn_s_setprio(0);
    }
  }

  float linv[4];
#pragma unroll
  for (int i = 0; i < 4; ++i) linv[i] = 1.f / __shfl(l_r, lg * 4 + i);
#pragma unroll
  for (int nd = 0; nd < 4; ++nd)
#pragma unroll
    for (int i = 0; i < 4; ++i) {
      int qrow = q0 + w * 16 + lg * 4 + i;
      O[((size_t)b * SS + qrow) * DD + h * HD + nd * 16 + lr] = f2bf(o[nd][i] * linv[i]);
    }
}

// ---------------- fused add + layernorm ----------------
// out = LN(a+b)*g + beta ; writes f32 (optional) and bf16 (optional)
__global__ __launch_bounds__(256) void ln_kernel(const float* __restrict__ a,
                                                 const float* __restrict__ bsrc,
                                                 const float* __restrict__ g,
                                                 const float* __restrict__ be,
                                                 float* __restrict__ outf,
                                                 unsigned short* __restrict__ outb) {
  const int row = blockIdx.x;
  const int t = threadIdx.x;
  const float4 av = ((const float4*)(a + (size_t)row * DD))[t];
  const float4 bv = ((const float4*)(bsrc + (size_t)row * DD))[t];
  float4 s;
  s.x = av.x + bv.x; s.y = av.y + bv.y; s.z = av.z + bv.z; s.w = av.w + bv.w;
  float sum = s.x + s.y + s.z + s.w;
  float sq = s.x * s.x + s.y * s.y + s.z * s.z + s.w * s.w;
#pragma unroll
  for (int mm = 1; mm < 64; mm <<= 1) {
    sum += __shfl_xor(sum, mm);
    sq += __shfl_xor(sq, mm);
  }
  __shared__ float red[8];
  const int w = t >> 6, l = t & 63;
  if (l == 0) { red[w] = sum; red[4 + w] = sq; }
  __syncthreads();
  sum = red[0] + red[1] + red[2] + red[3];
  sq = red[4] + red[5] + red[6] + red[7];
  const float mu = sum * (1.f / (float)DD);
  const float var = sq * (1.f / (float)DD) - mu * mu;
  const float rs = rsqrtf(var + 1e-5f);
  const float4 gv = ((const float4*)g)[t];
  const float4 bev = ((const float4*)be)[t];
  float4 y;
  y.x = (s.x - mu) * rs * gv.x + bev.x;
  y.y = (s.y - mu) * rs * gv.y + bev.y;
  y.z = (s.z - mu) * rs * gv.z + bev.z;
  y.w = (s.w - mu) * rs * gv.w + bev.w;
  if (outf) ((float4*)(outf + (size_t)row * DD))[t] = y;
  if (outb) {
    ushort4 u;
    u.x = f2bf(y.x); u.y = f2bf(y.y); u.z = f2bf(y.z); u.w = f2bf(y.w);
    ((ushort4*)(outb + (size_t)row * DD))[t] = u;
  }
}

// ---------------- host ----------------
extern "C" void kernel_launch(void* const* d_in, const int* in_sizes, int n_in,
                              void* d_out, int out_size, void* d_ws, size_t ws_size,
                              hipStream_t stream) {
  (void)in_sizes; (void)n_in; (void)out_size; (void)ws_size;
  const float* x = (const float*)d_in[0];
  const int* vlen = (const int*)d_in[1];
  const float* Wq = (const float*)d_in[2];
  const float* Wk = (const float*)d_in[3];
  const float* Wv = (const float*)d_in[4];
  const float* Wo = (const float*)d_in[5];
  const float* W1 = (const float*)d_in[6];
  const float* b1 = (const float*)d_in[7];
  const float* W2 = (const float*)d_in[8];
  const float* b2 = (const float*)d_in[9];
  const float* g1 = (const float*)d_in[10];
  const float* be1 = (const float*)d_in[11];
  const float* g2 = (const float*)d_in[12];
  const float* be2 = (const float*)d_in[13];
  float* out = (float*)d_out;

  char* ws = (char*)d_ws;
  size_t off = 0;
  auto alloc = [&](size_t bytes) {
    char* p = ws + off;
    off += (bytes + 255) & ~(size_t)255;
    return p;
  };
  unsigned short* xb = (unsigned short*)alloc((size_t)MM * DD * 2);
  // WqT/WkT/WvT MUST stay contiguous (fused QKV GEMM reads them as one 3072xK matrix)
  unsigned short* WqT = (unsigned short*)alloc((size_t)DD * DD * 2);
  unsigned short* WkT = (unsigned short*)alloc((size_t)DD * DD * 2);
  unsigned short* WvT = (unsigned short*)alloc((size_t)DD * DD * 2);
  unsigned short* WoT = (unsigned short*)alloc((size_t)DD * DD * 2);
  unsigned short* W1T = (unsigned short*)alloc((size_t)FF * DD * 2);
  unsigned short* W2T = (unsigned short*)alloc((size_t)DD * FF * 2);
  // Qb/Kbb/VTb MUST stay contiguous (EPI5 scatter offsets)
  unsigned short* Qb = (unsigned short*)alloc((size_t)MM * DD * 2);   // (B,H,S,HD)
  unsigned short* Kbb = (unsigned short*)alloc((size_t)MM * DD * 2);  // (B,H,S,HD)
  unsigned short* VTb = (unsigned short*)alloc((size_t)MM * DD * 2);  // (B,H,HD,S)
  unsigned short* attnb = (unsigned short*)alloc((size_t)MM * DD * 2);
  float* proj = (float*)alloc((size_t)MM * DD * 4);
  float* res1f = (float*)alloc((size_t)MM * DD * 4);
  unsigned short* res1b = (unsigned short*)alloc((size_t)MM * DD * 2);
  unsigned short* ff1 = Qb;  // alias: Qb..attnb contiguous = 67.1MB, all dead post-attn/Wo
  float* ff2 = proj;         // alias: proj dead after LN1
  (void)Kbb; (void)VTb;

  cast_bf16_k<<<MM * DD / 1024, 256, 0, stream>>>(x, xb);
  transpose_cast_k<<<dim3(32, 32), dim3(32, 8), 0, stream>>>(Wq, WqT, DD, DD);
  transpose_cast_k<<<dim3(32, 32), dim3(32, 8), 0, stream>>>(Wk, WkT, DD, DD);
  transpose_cast_k<<<dim3(32, 32), dim3(32, 8), 0, stream>>>(Wv, WvT, DD, DD);
  transpose_cast_k<<<dim3(32, 32), dim3(32, 8), 0, stream>>>(Wo, WoT, DD, DD);
  transpose_cast_k<<<dim3(128, 32), dim3(32, 8), 0, stream>>>(W1, W1T, DD, FF);
  transpose_cast_k<<<dim3(32, 128), dim3(32, 8), 0, stream>>>(W2, W2T, FF, DD);

  // fused QKV projection: BT = [WqT;WkT;WvT] (3072 x 1024), scatter epilogue
  gemm_bt<5><<<dim3(24, 64), 256, 0, stream>>>(xb, WqT, nullptr, Qb, 3072, DD);

  attn_kernel<<<dim3(2048), 256, 0, stream>>>(Qb, Kbb, VTb, vlen, attnb);

  gemm_bt<0><<<dim3(8, 64), 256, 0, stream>>>(attnb, WoT, nullptr, proj, DD, DD);
  ln_kernel<<<MM, 256, 0, stream>>>(proj, x, g1, be1, res1f, res1b);
  gemm_bt<3><<<dim3(32, 64), 256, 0, stream>>>(res1b, W1T, b1, ff1, FF, DD);
  gemm_bt<4><<<dim3(8, 64), 256, 0, stream>>>(ff1, W2T, b2, ff2, DD, FF);
  ln_kernel<<<MM, 256, 0, stream>>>(ff2, res1f, g2, be2, out, nullptr);
}

// Round 14
// 428.659 us; speedup vs baseline: 1.1500x; 1.0463x over previous
//
#include <hip/hip_runtime.h>
#include <hip/hip_bf16.h>
#include <stdint.h>

// Problem constants
#define BB 4
#define SS 2048
#define DD 1024
#define HH 16
#define HD 64
#define FF 4096
#define MM (BB * SS)   // 8192
#define BH (BB * HH)   // 64

typedef __bf16 bf16x8 __attribute__((ext_vector_type(8)));
typedef float f32x4 __attribute__((ext_vector_type(4)));

static __device__ __forceinline__ unsigned short f2bf(float f) {
  union { float f; unsigned u; } v; v.f = f;
  unsigned r = v.u + 0x7fffu + ((v.u >> 16) & 1u);
  return (unsigned short)(r >> 16);
}

static __device__ __forceinline__ float bf2f(unsigned short u) {
  union { unsigned u; float f; } v; v.u = ((unsigned)u) << 16; return v.f;
}

static __device__ __forceinline__ unsigned packbf2(float a, float b) {
  __hip_bfloat162 h = __float22bfloat162_rn(float2{a, b});  // low 16 = a
  union { __hip_bfloat162 h; unsigned u; } cv; cv.h = h; return cv.u;
}

// async global->LDS, 16B per lane. Dest must be wave-uniform base; HW adds lane*16.
#define GLD_LDS16(SRC, DST)                                          \
  __builtin_amdgcn_global_load_lds(                                  \
      (const __attribute__((address_space(1))) void*)(SRC),          \
      (__attribute__((address_space(3))) void*)(DST), 16, 0, 0)

// ---------------- cast f32 -> bf16 (x) ----------------
__global__ __launch_bounds__(256) void cast_bf16_k(const float* __restrict__ in,
                                                   unsigned short* __restrict__ out) {
  size_t i = ((size_t)blockIdx.x * 256 + threadIdx.x) * 4;
  float4 v = *(const float4*)(in + i);
  ushort4 u;
  u.x = f2bf(v.x); u.y = f2bf(v.y); u.z = f2bf(v.z); u.w = f2bf(v.w);
  *(ushort4*)(out + i) = u;
}

// ---------------- transpose + cast: W[K][N] f32 -> WT[N][K] bf16 ----------------
__global__ __launch_bounds__(256) void transpose_cast_k(const float* __restrict__ in,
                                                        unsigned short* __restrict__ out,
                                                        int K, int N) {
  __shared__ float tile[32][33];
  int n0 = blockIdx.x * 32, k0 = blockIdx.y * 32;
  int tx = threadIdx.x, ty = threadIdx.y;
#pragma unroll
  for (int i = 0; i < 32; i += 8)
    tile[ty + i][tx] = in[(size_t)(k0 + ty + i) * N + n0 + tx];
  __syncthreads();
#pragma unroll
  for (int i = 0; i < 32; i += 8)
    out[(size_t)(n0 + ty + i) * K + k0 + tx] = f2bf(tile[tx][ty + i]);
}

// ---------------- GEMM: C[M][N] = A[M][K] * BT[N][K]^T  (bf16 in, f32 accum) ----------
// 128x128 tile, BK=64, 4 waves (2x2), per-wave 4x4 fragments of 16x16x32 MFMA.
// LDS tiles XOR-swizzled on 16B chunks; XCD-aware chunked block swizzle (T1).
// __launch_bounds__(256,3): keep 3 blocks/CU resident (m97 plateau config).
// EPI: 3 = +bias, relu, bf16; 5 = fused QKV scatter; 6 = bf16 plain;
//      7 = +bias, bf16 plain.
template <int EPI>
__global__ __launch_bounds__(256, 3) void gemm_bt(const unsigned short* __restrict__ A,
                                                  const unsigned short* __restrict__ BT,
                                                  const float* __restrict__ bias,
                                                  void* __restrict__ Cout,
                                                  int N, int K) {
  __shared__ __align__(16) unsigned short Al[128 * 64];
  __shared__ __align__(16) unsigned short Bl[128 * 64];
  const int t = threadIdx.x;
  const int w = t >> 6, l = t & 63, lr = l & 15, lg = l >> 4;
  const int gx = gridDim.x;
  int lin = blockIdx.y * gx + blockIdx.x;
  const int nb = gx * gridDim.y;
  lin = (lin & 7) * (nb >> 3) + (lin >> 3);
  const int brow = (lin / gx) << 7, bcol = (lin % gx) << 7;
  const int wr = w >> 1, wc = w & 1;
  f32x4 acc[4][4] = {};

  for (int kt = 0; kt < K; kt += 64) {
    __syncthreads();  // previous tile's reads done before overwrite
#pragma unroll
    for (int is = 0; is < 4; ++is) {
      int c = is * 256 + t;          // chunk index 0..1023 (16B chunks)
      int row = c >> 3;
      int js = (c & 7) ^ (row & 7);  // inverse-swizzled source chunk
      GLD_LDS16(A + (size_t)(brow + row) * K + kt + js * 8,
                &Al[(size_t)(is * 256 + w * 64) * 8]);
      GLD_LDS16(BT + (size_t)(bcol + row) * K + kt + js * 8,
                &Bl[(size_t)(is * 256 + w * 64) * 8]);
    }
    __syncthreads();  // compiler drains vmcnt(0) before barrier
#pragma unroll
    for (int kk = 0; kk < 2; ++kk) {
      bf16x8 af[4], bfr[4];
#pragma unroll
      for (int m = 0; m < 4; ++m) {
        int row = wr * 64 + m * 16 + lr;
        af[m] = *(const bf16x8*)&Al[row * 64 + (((kk * 4 + lg) ^ (row & 7)) << 3)];
      }
#pragma unroll
      for (int n = 0; n < 4; ++n) {
        int row = wc * 64 + n * 16 + lr;
        bfr[n] = *(const bf16x8*)&Bl[row * 64 + (((kk * 4 + lg) ^ (row & 7)) << 3)];
      }
#pragma unroll
      for (int m = 0; m < 4; ++m)
#pragma unroll
        for (int n = 0; n < 4; ++n)
          acc[m][n] = __builtin_amdgcn_mfma_f32_16x16x32_bf16(af[m], bfr[n], acc[m][n], 0, 0, 0);
    }
  }

  // epilogue: C/D layout row=(l>>4)*4+i, col=l&15  (HW-verified)
#pragma unroll
  for (int m = 0; m < 4; ++m) {
#pragma unroll
    for (int n = 0; n < 4; ++n) {
      int col = bcol + wc * 64 + n * 16 + lr;
      float bv = 0.f;
      if (EPI == 3 || EPI == 7) bv = bias[col];
#pragma unroll
      for (int i = 0; i < 4; ++i) {
        int row = brow + wr * 64 + m * 16 + lg * 4 + i;
        float v = acc[m][n][i];
        if (EPI == 3) {
          v += bv; v = v > 0.f ? v : 0.f;
          ((unsigned short*)Cout)[(size_t)row * N + col] = f2bf(v);
        } else if (EPI == 6) {
          ((unsigned short*)Cout)[(size_t)row * N + col] = f2bf(v);
        } else if (EPI == 7) {
          v += bv;
          ((unsigned short*)Cout)[(size_t)row * N + col] = f2bf(v);
        } else if (EPI == 5) {
          int b = row >> 11, s = row & 2047;
          int which = col >> 10, cin = col & 1023;
          int h = cin >> 6, hd = cin & 63;
          unsigned short* qb = (unsigned short*)Cout;
          if (which == 0) {        // Q, pre-scaled by 1/sqrt(HD) (exact pow2)
            qb[(((size_t)(b * HH + h)) * SS + s) * HD + hd] = f2bf(v * 0.125f);
          } else if (which == 1) { // K
            (qb + (size_t)MM * DD)[(((size_t)(b * HH + h)) * SS + s) * HD + hd] = f2bf(v);
          } else {                 // V, transposed (B,H,HD,S)
            (qb + 2 * (size_t)MM * DD)[(((size_t)(b * HH + h)) * HD + hd) * SS + s] = f2bf(v);
          }
        }
      }
    }
  }
}

// ---------------- flash attention, swapped-QK^T (R3-verified) + T5 setprio ---------
// Flat grid 2048: bh = gid&63 (batch-interleaved for load balance), qb = gid>>6.
// 4 waves x 16 q-rows. KVBLK=64, HD=64. Q bf16 (pre-scaled 0.125) in regs.
__global__ __launch_bounds__(256, 4) void attn_kernel(const unsigned short* __restrict__ Q,
                                                      const unsigned short* __restrict__ Kg,
                                                      const unsigned short* __restrict__ VT,
                                                      const int* __restrict__ vlens,
                                                      unsigned short* __restrict__ O) {
  __shared__ __align__(16) unsigned short Kt[64 * 64];  // rows = keys
  __shared__ __align__(16) unsigned short Vt[64 * 64];  // rows = d, cols = keys
  const int t = threadIdx.x;
  const int w = t >> 6, l = t & 63, lr = l & 15, lg = l >> 4;
  const int gid = blockIdx.x;
  const int bh = gid & 63, qb = gid >> 6;
  const int b = bh >> 4, h = bh & 15;
  const int q0 = qb << 6;
  const int vl = vlens[b];
  const size_t base = (size_t)bh * SS * HD;

  bf16x8 qf[2];
  {
    const int qrow = q0 + w * 16 + lr;
    qf[0] = *(const bf16x8*)(Q + base + (size_t)qrow * HD + lg * 8);
    qf[1] = *(const bf16x8*)(Q + base + (size_t)qrow * HD + 32 + lg * 8);
  }
  f32x4 o[4] = {};
  float m_r = -3.0e38f, l_r = 0.f;  // reduction domain: q = lr (replicated over lg)

  const int nkv = (vl + 63) >> 6;
  for (int kbi = 0; kbi < nkv; ++kbi) {
    const int kb = kbi << 6;
    __syncthreads();
#pragma unroll
    for (int is = 0; is < 2; ++is) {
      int c = is * 256 + t;          // 512 chunks per 8KB tile
      int row = c >> 3;
      int js = (c & 7) ^ (row & 7);
      GLD_LDS16(Kg + base + (size_t)(kb + row) * HD + js * 8,
                &Kt[(is * 256 + w * 64) * 8]);
      GLD_LDS16(VT + base + (size_t)row * SS + kb + js * 8,
                &Vt[(is * 256 + w * 64) * 8]);
    }
    __syncthreads();

    // swapped QK^T: s[n] D-layout row(key)=n*16+lg*4+i, col(q)=lr
    f32x4 s[4] = {};
    __builtin_amdgcn_s_setprio(1);
#pragma unroll
    for (int kk = 0; kk < 2; ++kk)
#pragma unroll
      for (int n = 0; n < 4; ++n) {
        int row = n * 16 + lr;
        bf16x8 kf = *(const bf16x8*)&Kt[row * 64 + (((kk * 4 + lg) ^ (row & 7)) << 3)];
        s[n] = __builtin_amdgcn_mfma_f32_16x16x32_bf16(kf, qf[kk], s[n], 0, 0, 0);
      }
    __builtin_amdgcn_s_setprio(0);

    // mask + lane-local max tree
    float sv[16];
    const int kbase = kb + lg * 4;
#pragma unroll
    for (int n = 0; n < 4; ++n)
#pragma unroll
      for (int i = 0; i < 4; ++i) {
        float v = s[n][i];
        if (kbase + n * 16 + i >= vl) v = -1.0e30f;
        sv[n * 4 + i] = v;
      }
    float tm[16];
#pragma unroll
    for (int j = 0; j < 16; ++j) tm[j] = sv[j];
#pragma unroll
    for (int st = 8; st >= 1; st >>= 1)
#pragma unroll
      for (int j = 0; j < 8; ++j)
        if (j < st) tm[j] = fmaxf(tm[j], tm[j + st]);
    float rm = tm[0];
    rm = fmaxf(rm, __shfl_xor(rm, 16));
    rm = fmaxf(rm, __shfl_xor(rm, 32));

    // defer-max (THR=8)
    if (__any(rm > m_r + 8.f)) {
      float mnew = fmaxf(m_r, rm);
      float alpha = __expf(m_r - mnew);
      m_r = mnew;
      l_r *= alpha;
      float af[4];
#pragma unroll
      for (int i = 0; i < 4; ++i) af[i] = __shfl(alpha, lg * 4 + i);  // accum domain q=lg*4+i
#pragma unroll
      for (int n = 0; n < 4; ++n)
#pragma unroll
        for (int i = 0; i < 4; ++i) o[n][i] *= af[i];
    }

    // exp + lane-local sum tree
    float p[16];
#pragma unroll
    for (int j = 0; j < 16; ++j) p[j] = __expf(sv[j] - m_r);
    float ts[16];
#pragma unroll
    for (int j = 0; j < 16; ++j) ts[j] = p[j];
#pragma unroll
    for (int st = 8; st >= 1; st >>= 1)
#pragma unroll
      for (int j = 0; j < 8; ++j)
        if (j < st) ts[j] += ts[j + st];
    float rs = ts[0];
    rs += __shfl_xor(rs, 16);
    rs += __shfl_xor(rs, 32);
    l_r += rs;

    // pack: d[n][di] = bf16 pair for keys (n*16+lg*4+2di, +1), q=lr
    unsigned pd[4][2];
#pragma unroll
    for (int n = 0; n < 4; ++n) {
      pd[n][0] = packbf2(p[n * 4 + 0], p[n * 4 + 1]);
      pd[n][1] = packbf2(p[n * 4 + 2], p[n * 4 + 3]);
    }

    // PV: A-frag lane needs P[q=lr][k=kk*32+lg*8+j]; dword jj from source lane
    // lr+16*(2*(lg&1)+(jj>>1)), reg d[2kk+(lg>>1)][jj&1].
#pragma unroll
    for (int kk = 0; kk < 2; ++kk) {
      unsigned pa[4];
#pragma unroll
      for (int jj = 0; jj < 4; ++jj) {
        int src = lr + 16 * (2 * (lg & 1) + (jj >> 1));
        unsigned rlo = __shfl(pd[2 * kk + 0][jj & 1], src);
        unsigned rhi = __shfl(pd[2 * kk + 1][jj & 1], src);
        pa[jj] = (lg & 2) ? rhi : rlo;
      }
      union { unsigned u[4]; bf16x8 v; } pb;
      pb.u[0] = pa[0]; pb.u[1] = pa[1]; pb.u[2] = pa[2]; pb.u[3] = pa[3];
      __builtin_amdgcn_s_setprio(1);
#pragma unroll
      for (int nd = 0; nd < 4; ++nd) {
        int row = nd * 16 + lr;
        bf16x8 vf = *(const bf16x8*)&Vt[row * 64 + (((kk * 4 + lg) ^ (row & 7)) << 3)];
        o[nd] = __builtin_amdgcn_mfma_f32_16x16x32_bf16(pb.v, vf, o[nd], 0, 0, 0);
      }
      __builtin_amdgcn_s_setprio(0);
    }
  }

  float linv[4];
#pragma unroll
  for (int i = 0; i < 4; ++i) linv[i] = 1.f / __shfl(l_r, lg * 4 + i);
#pragma unroll
  for (int nd = 0; nd < 4; ++nd)
#pragma unroll
    for (int i = 0; i < 4; ++i) {
      int qrow = q0 + w * 16 + lg * 4 + i;
      O[((size_t)b * SS + qrow) * DD + h * HD + nd * 16 + lr] = f2bf(o[nd][i] * linv[i]);
    }
}

// ---------------- fused add + layernorm (mixed input dtypes) ----------------
// out = LN(a+b)*g + beta.  ABF/BBF: 1 = bf16 input, 0 = f32 input.
// Writes f32 (optional) and bf16 (optional).
template <int ABF, int BBF>
__global__ __launch_bounds__(256) void ln_kernel(const void* __restrict__ a,
                                                 const void* __restrict__ bsrc,
                                                 const float* __restrict__ g,
                                                 const float* __restrict__ be,
                                                 float* __restrict__ outf,
                                                 unsigned short* __restrict__ outb) {
  const int row = blockIdx.x;
  const int t = threadIdx.x;
  float4 av, bv;
  if (ABF) {
    ushort4 u = ((const ushort4*)((const unsigned short*)a + (size_t)row * DD))[t];
    av.x = bf2f(u.x); av.y = bf2f(u.y); av.z = bf2f(u.z); av.w = bf2f(u.w);
  } else {
    av = ((const float4*)((const float*)a + (size_t)row * DD))[t];
  }
  if (BBF) {
    ushort4 u = ((const ushort4*)((const unsigned short*)bsrc + (size_t)row * DD))[t];
    bv.x = bf2f(u.x); bv.y = bf2f(u.y); bv.z = bf2f(u.z); bv.w = bf2f(u.w);
  } else {
    bv = ((const float4*)((const float*)bsrc + (size_t)row * DD))[t];
  }
  float4 s;
  s.x = av.x + bv.x; s.y = av.y + bv.y; s.z = av.z + bv.z; s.w = av.w + bv.w;
  float sum = s.x + s.y + s.z + s.w;
  float sq = s.x * s.x + s.y * s.y + s.z * s.z + s.w * s.w;
#pragma unroll
  for (int mm = 1; mm < 64; mm <<= 1) {
    sum += __shfl_xor(sum, mm);
    sq += __shfl_xor(sq, mm);
  }
  __shared__ float red[8];
  const int w = t >> 6, l = t & 63;
  if (l == 0) { red[w] = sum; red[4 + w] = sq; }
  __syncthreads();
  sum = red[0] + red[1] + red[2] + red[3];
  sq = red[4] + red[5] + red[6] + red[7];
  const float mu = sum * (1.f / (float)DD);
  const float var = sq * (1.f / (float)DD) - mu * mu;
  const float rs = rsqrtf(var + 1e-5f);
  const float4 gv = ((const float4*)g)[t];
  const float4 bev = ((const float4*)be)[t];
  float4 y;
  y.x = (s.x - mu) * rs * gv.x + bev.x;
  y.y = (s.y - mu) * rs * gv.y + bev.y;
  y.z = (s.z - mu) * rs * gv.z + bev.z;
  y.w = (s.w - mu) * rs * gv.w + bev.w;
  if (outf) ((float4*)(outf + (size_t)row * DD))[t] = y;
  if (outb) {
    ushort4 u;
    u.x = f2bf(y.x); u.y = f2bf(y.y); u.z = f2bf(y.z); u.w = f2bf(y.w);
    ((ushort4*)(outb + (size_t)row * DD))[t] = u;
  }
}

// ---------------- host ----------------
extern "C" void kernel_launch(void* const* d_in, const int* in_sizes, int n_in,
                              void* d_out, int out_size, void* d_ws, size_t ws_size,
                              hipStream_t stream) {
  (void)in_sizes; (void)n_in; (void)out_size; (void)ws_size;
  const float* x = (const float*)d_in[0];
  const int* vlen = (const int*)d_in[1];
  const float* Wq = (const float*)d_in[2];
  const float* Wk = (const float*)d_in[3];
  const float* Wv = (const float*)d_in[4];
  const float* Wo = (const float*)d_in[5];
  const float* W1 = (const float*)d_in[6];
  const float* b1 = (const float*)d_in[7];
  const float* W2 = (const float*)d_in[8];
  const float* b2 = (const float*)d_in[9];
  const float* g1 = (const float*)d_in[10];
  const float* be1 = (const float*)d_in[11];
  const float* g2 = (const float*)d_in[12];
  const float* be2 = (const float*)d_in[13];
  float* out = (float*)d_out;

  char* ws = (char*)d_ws;
  size_t off = 0;
  auto alloc = [&](size_t bytes) {
    char* p = ws + off;
    off += (bytes + 255) & ~(size_t)255;
    return p;
  };
  unsigned short* xb = (unsigned short*)alloc((size_t)MM * DD * 2);
  // WqT/WkT/WvT MUST stay contiguous (fused QKV GEMM reads them as one 3072xK matrix)
  unsigned short* WqT = (unsigned short*)alloc((size_t)DD * DD * 2);
  unsigned short* WkT = (unsigned short*)alloc((size_t)DD * DD * 2);
  unsigned short* WvT = (unsigned short*)alloc((size_t)DD * DD * 2);
  unsigned short* WoT = (unsigned short*)alloc((size_t)DD * DD * 2);
  unsigned short* W1T = (unsigned short*)alloc((size_t)FF * DD * 2);
  unsigned short* W2T = (unsigned short*)alloc((size_t)DD * FF * 2);
  // Qb/Kbb/VTb MUST stay contiguous (EPI5 scatter offsets)
  unsigned short* Qb = (unsigned short*)alloc((size_t)MM * DD * 2);   // (B,H,S,HD)
  unsigned short* Kbb = (unsigned short*)alloc((size_t)MM * DD * 2);  // (B,H,S,HD)
  unsigned short* VTb = (unsigned short*)alloc((size_t)MM * DD * 2);  // (B,H,HD,S)
  unsigned short* attnb = (unsigned short*)alloc((size_t)MM * DD * 2);
  unsigned short* projb = (unsigned short*)alloc((size_t)MM * DD * 2);  // bf16 now
  unsigned short* res1b = (unsigned short*)alloc((size_t)MM * DD * 2);
  unsigned short* ff1 = Qb;    // alias: Qb..attnb contiguous = 67.1MB, dead post-attn/Wo
  unsigned short* ff2b = projb;  // alias: proj dead after LN1
  (void)Kbb; (void)VTb;

  cast_bf16_k<<<MM * DD / 1024, 256, 0, stream>>>(x, xb);
  transpose_cast_k<<<dim3(32, 32), dim3(32, 8), 0, stream>>>(Wq, WqT, DD, DD);
  transpose_cast_k<<<dim3(32, 32), dim3(32, 8), 0, stream>>>(Wk, WkT, DD, DD);
  transpose_cast_k<<<dim3(32, 32), dim3(32, 8), 0, stream>>>(Wv, WvT, DD, DD);
  transpose_cast_k<<<dim3(32, 32), dim3(32, 8), 0, stream>>>(Wo, WoT, DD, DD);
  transpose_cast_k<<<dim3(128, 32), dim3(32, 8), 0, stream>>>(W1, W1T, DD, FF);
  transpose_cast_k<<<dim3(32, 128), dim3(32, 8), 0, stream>>>(W2, W2T, FF, DD);

  // fused QKV projection: BT = [WqT;WkT;WvT] (3072 x 1024), scatter epilogue
  gemm_bt<5><<<dim3(24, 64), 256, 0, stream>>>(xb, WqT, nullptr, Qb, 3072, DD);

  attn_kernel<<<dim3(2048), 256, 0, stream>>>(Qb, Kbb, VTb, vlen, attnb);

  // Wo projection -> bf16 proj (16MB instead of 32MB f32)
  gemm_bt<6><<<dim3(8, 64), 256, 0, stream>>>(attnb, WoT, nullptr, projb, DD, DD);
  // LN1: bf16 proj + f32 x -> bf16 res1 only (res1f dropped)
  ln_kernel<1, 0><<<MM, 256, 0, stream>>>(projb, x, g1, be1, nullptr, res1b);
  gemm_bt<3><<<dim3(32, 64), 256, 0, stream>>>(res1b, W1T, b1, ff1, FF, DD);
  // FF2 -> bf16 ff2 (+bias)
  gemm_bt<7><<<dim3(8, 64), 256, 0, stream>>>(ff1, W2T, b2, ff2b, DD, FF);
  // LN2: bf16 ff2 + bf16 res1 -> f32 out
  ln_kernel<1, 1><<<MM, 256, 0, stream>>>(ff2b, res1b, g2, be2, out, nullptr);
}